// Round 1
// baseline (106.806 us; speedup 1.0000x reference)
//
#include <hip/hip_runtime.h>
#include <cstdint>
#include <cstddef>

#define LRALPHA 0.2f

typedef _Float16 half8 __attribute__((ext_vector_type(8)));
typedef float f32x4 __attribute__((ext_vector_type(4)));

// ---------------------------------------------------------------------------
// Kernel 1: Wh = h @ W  (8192x512 @ 512x64), writes:
//   whT  : f16 [64][8192]   (transposed, feeds MFMA B-fragments directly)
//   wh1  : f32 [8192]       (Wh @ a[:64])
//   wh2  : f32 [8192]       (Wh @ a[64:])
// Block: 256 thr, 32 rows x 64 cols tile, K staged in 32-chunks.
// ---------------------------------------------------------------------------
__global__ __launch_bounds__(256) void k1_wh(
    const float* __restrict__ h, const float* __restrict__ W, const float* __restrict__ a,
    _Float16* __restrict__ whT, float* __restrict__ wh1, float* __restrict__ wh2)
{
  __shared__ __align__(16) float h_lds[32][34];   // [k][row], pad keeps 8B align
  __shared__ __align__(16) float w_lds[32][64];   // [k][col]
  __shared__ __align__(16) _Float16 whT_l[64][32];

  const int t = threadIdx.x;
  const int tx = t & 15, ty = t >> 4;
  const int i0 = blockIdx.x * 32;

  const int hrow = t >> 3, hk4 = (t & 7) * 4;   // h staging: 32 rows x 4 k each
  const int wk = t >> 3, wc = (t & 7) * 8;      // W staging: 32 k x 8 cols each

  float acc00 = 0, acc01 = 0, acc02 = 0, acc03 = 0;
  float acc10 = 0, acc11 = 0, acc12 = 0, acc13 = 0;

  float4 hv  = *reinterpret_cast<const float4*>(&h[(size_t)(i0 + hrow) * 512 + hk4]);
  float4 wv0 = *reinterpret_cast<const float4*>(&W[(size_t)wk * 64 + wc]);
  float4 wv1 = *reinterpret_cast<const float4*>(&W[(size_t)wk * 64 + wc + 4]);

  for (int k0 = 0; k0 < 512; k0 += 32) {
    h_lds[hk4 + 0][hrow] = hv.x;
    h_lds[hk4 + 1][hrow] = hv.y;
    h_lds[hk4 + 2][hrow] = hv.z;
    h_lds[hk4 + 3][hrow] = hv.w;
    *reinterpret_cast<float4*>(&w_lds[wk][wc])     = wv0;
    *reinterpret_cast<float4*>(&w_lds[wk][wc + 4]) = wv1;
    __syncthreads();
    if (k0 + 32 < 512) {  // software prefetch next tile under compute
      hv  = *reinterpret_cast<const float4*>(&h[(size_t)(i0 + hrow) * 512 + k0 + 32 + hk4]);
      wv0 = *reinterpret_cast<const float4*>(&W[(size_t)(k0 + 32 + wk) * 64 + wc]);
      wv1 = *reinterpret_cast<const float4*>(&W[(size_t)(k0 + 32 + wk) * 64 + wc + 4]);
    }
#pragma unroll
    for (int kk = 0; kk < 32; ++kk) {
      float2 av = *reinterpret_cast<const float2*>(&h_lds[kk][ty * 2]);
      float4 bv = *reinterpret_cast<const float4*>(&w_lds[kk][tx * 4]);
      acc00 += av.x * bv.x; acc01 += av.x * bv.y; acc02 += av.x * bv.z; acc03 += av.x * bv.w;
      acc10 += av.y * bv.x; acc11 += av.y * bv.y; acc12 += av.y * bv.z; acc13 += av.y * bv.w;
    }
    __syncthreads();
  }

  // Wh1/Wh2: dot rows with a1/a2, reduce across the 16 tx lanes
  const float a10 = a[tx * 4 + 0], a11 = a[tx * 4 + 1], a12 = a[tx * 4 + 2], a13 = a[tx * 4 + 3];
  const float a20 = a[64 + tx * 4 + 0], a21 = a[64 + tx * 4 + 1], a22 = a[64 + tx * 4 + 2], a23 = a[64 + tx * 4 + 3];
  float s1_0 = acc00 * a10 + acc01 * a11 + acc02 * a12 + acc03 * a13;
  float s1_1 = acc10 * a10 + acc11 * a11 + acc12 * a12 + acc13 * a13;
  float s2_0 = acc00 * a20 + acc01 * a21 + acc02 * a22 + acc03 * a23;
  float s2_1 = acc10 * a20 + acc11 * a21 + acc12 * a22 + acc13 * a23;
#pragma unroll
  for (int m = 1; m < 16; m <<= 1) {
    s1_0 += __shfl_xor(s1_0, m); s1_1 += __shfl_xor(s1_1, m);
    s2_0 += __shfl_xor(s2_0, m); s2_1 += __shfl_xor(s2_1, m);
  }
  if (tx == 0) {
    wh1[i0 + ty * 2 + 0] = s1_0; wh1[i0 + ty * 2 + 1] = s1_1;
    wh2[i0 + ty * 2 + 0] = s2_0; wh2[i0 + ty * 2 + 1] = s2_1;
  }

  // WhT f16 via LDS round-trip for coalesced 16B stores
  whT_l[tx * 4 + 0][ty * 2 + 0] = (_Float16)acc00;
  whT_l[tx * 4 + 1][ty * 2 + 0] = (_Float16)acc01;
  whT_l[tx * 4 + 2][ty * 2 + 0] = (_Float16)acc02;
  whT_l[tx * 4 + 3][ty * 2 + 0] = (_Float16)acc03;
  whT_l[tx * 4 + 0][ty * 2 + 1] = (_Float16)acc10;
  whT_l[tx * 4 + 1][ty * 2 + 1] = (_Float16)acc11;
  whT_l[tx * 4 + 2][ty * 2 + 1] = (_Float16)acc12;
  whT_l[tx * 4 + 3][ty * 2 + 1] = (_Float16)acc13;
  __syncthreads();
  {
    const int c = t >> 2, r8 = (t & 3) * 8;
    half8 v = *reinterpret_cast<const half8*>(&whT_l[c][r8]);
    *reinterpret_cast<half8*>(&whT[(size_t)c * 8192 + i0 + r8]) = v;
  }
}

// ---------------------------------------------------------------------------
// Kernel 1b: G = max(wh2)  (global unmasked max -> safe softmax shift)
// ---------------------------------------------------------------------------
__global__ __launch_bounds__(256) void k1b_max(const float* __restrict__ wh2,
                                               float* __restrict__ G)
{
  const int t = threadIdx.x;
  float m = -1e30f;
  for (int i = t; i < 8192; i += 256) m = fmaxf(m, wh2[i]);
#pragma unroll
  for (int mask = 32; mask >= 1; mask >>= 1) m = fmaxf(m, __shfl_xor(m, mask));
  __shared__ float wm[4];
  if ((t & 63) == 0) wm[t >> 6] = m;
  __syncthreads();
  if (t == 0) G[0] = fmaxf(fmaxf(wm[0], wm[1]), fmaxf(wm[2], wm[3]));
}

// ---------------------------------------------------------------------------
// Kernel 2: fused masked-softmax + PV (single pass over adj).
// 256 blocks x 512 thr. Block = 32 rows. Two 4-wave groups split-K over
// interleaved 64-j chunks; p tile f16 in XOR-swizzled LDS (dbuf, 1 barrier
// per chunk); PV via mfma_f32_16x16x32_f16; per-row denom in f32.
// ---------------------------------------------------------------------------
__global__ __launch_bounds__(512) void k2_attn(
    const int* __restrict__ adj, const _Float16* __restrict__ whT,
    const float* __restrict__ wh1, const float* __restrict__ wh2,
    const float* __restrict__ Gp, float* __restrict__ out)
{
  __shared__ __align__(16) unsigned char smraw[16384];  // p[2][2][32][64] f16, reused as o[32][64] f32
  __shared__ float denom_s[64];
  _Float16* P = reinterpret_cast<_Float16*>(smraw);
  float* O = reinterpret_cast<float*>(smraw);

  const int t = threadIdx.x;
  const int g = t >> 8;           // K-group
  const int tg = t & 255;
  const int lane = t & 63;
  const int wg = (t >> 6) & 3;    // wave within group
  const int i0 = blockIdx.x * 32;

  if (t < 64) denom_s[t] = 0.f;

  const float Gv = Gp[0];
  const int prow = tg >> 3;       // 0..31 : row this thread scores
  const int pc8 = tg & 7;         // 8-j chunk within 64-j tile
  const float w1r = wh1[i0 + prow];
  const float mx = w1r + Gv;
  const float mh = fmaxf(mx, LRALPHA * mx);   // per-row safe shift (>= all scores)
  const int* adj_row = adj + (size_t)(i0 + prow) * 8192 + pc8 * 8;
  const float* wh2o = wh2 + pc8 * 8;

  const int rt = wg >> 1, cp = wg & 1;        // rowtile / colpair of this wave
  const int arow = rt * 16 + (lane & 15);
  const int kgrp = lane >> 4;
  const _Float16* bbase = whT + (size_t)(cp * 32 + (lane & 15)) * 8192 + kgrp * 8;

  f32x4 acc0 = {0.f, 0.f, 0.f, 0.f}, acc1 = {0.f, 0.f, 0.f, 0.f};

  int4 na0, na1; float4 nw0, nw1;
  {
    const int j0 = g * 64;
    na0 = *reinterpret_cast<const int4*>(adj_row + j0);
    na1 = *reinterpret_cast<const int4*>(adj_row + j0 + 4);
    nw0 = *reinterpret_cast<const float4*>(wh2o + j0);
    nw1 = *reinterpret_cast<const float4*>(wh2o + j0 + 4);
  }
  __syncthreads();  // denom init visible before first accumulate

  for (int ci = 0; ci < 64; ++ci) {
    const int j0 = (2 * ci + g) * 64;
    const int buf = ci & 1;
    const int4 a0 = na0, a1 = na1;
    const float4 w0 = nw0, w1v = nw1;

    // B fragments straight from global WhT (L2-resident, 16B per lane)
    const _Float16* bp = bbase + j0;
    half8 bf00 = *reinterpret_cast<const half8*>(bp);
    half8 bf01 = *reinterpret_cast<const half8*>(bp + (size_t)16 * 8192);
    half8 bf10 = *reinterpret_cast<const half8*>(bp + 32);
    half8 bf11 = *reinterpret_cast<const half8*>(bp + (size_t)16 * 8192 + 32);

    // prefetch next chunk's adj/wh2 (latency hidden under p-compute + barrier + MFMA)
    if (ci < 63) {
      const int jn = (2 * ci + 2 + g) * 64;
      na0 = *reinterpret_cast<const int4*>(adj_row + jn);
      na1 = *reinterpret_cast<const int4*>(adj_row + jn + 4);
      nw0 = *reinterpret_cast<const float4*>(wh2o + jn);
      nw1 = *reinterpret_cast<const float4*>(wh2o + jn + 4);
    }

    // p = adj ? exp(lrelu(w1+w2) - mh) : 0   (always <= 1)
    half8 pv;
    float ps = 0.f;
#define DO_E(e, AV, WV) { float s_ = w1r + (WV); s_ = fmaxf(s_, LRALPHA * s_); \
    float p_ = ((AV) > 0) ? __expf(s_ - mh) : 0.f; ps += p_; pv[e] = (_Float16)p_; }
    DO_E(0, a0.x, w0.x)  DO_E(1, a0.y, w0.y)  DO_E(2, a0.z, w0.z)  DO_E(3, a0.w, w0.w)
    DO_E(4, a1.x, w1v.x) DO_E(5, a1.y, w1v.y) DO_E(6, a1.z, w1v.z) DO_E(7, a1.w, w1v.w)
#undef DO_E

    // denom: reduce the 8 lanes covering this row's 64-j tile
    float r = ps;
    r += __shfl_xor(r, 1); r += __shfl_xor(r, 2); r += __shfl_xor(r, 4);
    if (pc8 == 0) denom_s[g * 32 + prow] += r;

    // store p tile, XOR-swizzled 16B chunks (kills the 128B-stride bank conflict)
    {
      const int chunk = pc8 ^ (prow & 7);
      *reinterpret_cast<half8*>(&P[(((g << 1) | buf) << 11) + (prow << 6) + (chunk << 3)]) = pv;
    }
    __syncthreads();

    // MFMA: A = p[16 rows x 32 j] from LDS, B = WhT frags
    const int base = (((g << 1) | buf) << 11) + (arow << 6);
    const int cA0 = (kgrp ^ (arow & 7)) << 3;
    const int cA1 = ((4 + kgrp) ^ (arow & 7)) << 3;
    half8 af0 = *reinterpret_cast<const half8*>(&P[base + cA0]);
    half8 af1 = *reinterpret_cast<const half8*>(&P[base + cA1]);
    acc0 = __builtin_amdgcn_mfma_f32_16x16x32_f16(af0, bf00, acc0, 0, 0, 0);
    acc1 = __builtin_amdgcn_mfma_f32_16x16x32_f16(af0, bf01, acc1, 0, 0, 0);
    acc0 = __builtin_amdgcn_mfma_f32_16x16x32_f16(af1, bf10, acc0, 0, 0, 0);
    acc1 = __builtin_amdgcn_mfma_f32_16x16x32_f16(af1, bf11, acc1, 0, 0, 0);
  }

  __syncthreads();
  // combine the two K-groups' accumulators in LDS, then divide + elu + store
  const int orow = rt * 16 + kgrp * 4;
  const int ocol = cp * 32 + (lane & 15);
  if (g == 0) {
#pragma unroll
    for (int q = 0; q < 4; ++q) {
      O[(orow + q) * 64 + ocol]      = acc0[q];
      O[(orow + q) * 64 + ocol + 16] = acc1[q];
    }
  }
  __syncthreads();
  if (g == 1) {
#pragma unroll
    for (int q = 0; q < 4; ++q) {
      O[(orow + q) * 64 + ocol]      += acc0[q];
      O[(orow + q) * 64 + ocol + 16] += acc1[q];
    }
  }
  __syncthreads();
  {
    const int row = t >> 4, c4 = (t & 15) * 4;
    const float d = denom_s[row] + denom_s[32 + row];
    const float inv = 1.0f / d;
    float4 v = *reinterpret_cast<const float4*>(&O[row * 64 + c4]);
    float4 o;
    o.x = v.x * inv; o.y = v.y * inv; o.z = v.z * inv; o.w = v.w * inv;
    o.x = o.x > 0.f ? o.x : __expf(o.x) - 1.f;
    o.y = o.y > 0.f ? o.y : __expf(o.y) - 1.f;
    o.z = o.z > 0.f ? o.z : __expf(o.z) - 1.f;
    o.w = o.w > 0.f ? o.w : __expf(o.w) - 1.f;
    *reinterpret_cast<float4*>(&out[(size_t)(i0 + row) * 64 + c4]) = o;
  }
}

// ---------------------------------------------------------------------------
extern "C" void kernel_launch(void* const* d_in, const int* in_sizes, int n_in,
                              void* d_out, int out_size, void* d_ws, size_t ws_size,
                              hipStream_t stream) {
  const float* h   = (const float*)d_in[0];
  const int*   adj = (const int*)d_in[1];
  const float* W   = (const float*)d_in[2];
  const float* a   = (const float*)d_in[3];
  float* out = (float*)d_out;

  char* ws = (char*)d_ws;
  _Float16* whT = (_Float16*)ws;                          // 64*8192*2 = 1 MiB
  float* wh1 = (float*)(ws + (1 << 20));                  // 32 KiB
  float* wh2 = (float*)(ws + (1 << 20) + 32768);          // 32 KiB
  float* G   = (float*)(ws + (1 << 20) + 65536);          // 4 B

  k1_wh<<<dim3(256), dim3(256), 0, stream>>>(h, W, a, whT, wh1, wh2);
  k1b_max<<<dim3(1), dim3(256), 0, stream>>>(wh2, G);
  k2_attn<<<dim3(256), dim3(512), 0, stream>>>(adj, whT, wh1, wh2, G, out);
}